// Round 13
// baseline (89.657 us; speedup 1.0000x reference)
//
#include <hip/hip_runtime.h>

#define HDIM 1024
#define NW 18                 // 6 gate rows + 12 expert rows (e*2+l)
#define NTHREADS 256
#define RPT 8                 // rows per lane
#define ROWS_PER_BLOCK 256    // 4 waves x 64 rows
#define NJ 32                 // j-steps of 32 floats (128B) per row

typedef float f32x4 __attribute__((ext_vector_type(4)));

// R13 = R11 (best, 51.3us) + temporal load smoothing + full-residue phase.
//  - Queueing arithmetic: memory pipe saturated (eff. latency ~3400cyc >> 900);
//    TLP/deeper prefetch provably null (R4/R12). Last mechanism: per-wave loads
//    issue as 8-deep bursts every ~1150cyc -> channel-queue oscillation.
//    sched_group_barrier pins [32 VALU][1 VMEM] per w-iteration so the 8
//    prefetch loads spread uniformly across the compute block. DS reads left
//    unconstrained (preserve compiler lgkmcnt lookahead).
//  - Phase: blk*9 (gcd(9,32)=1 -> all 32 residues) + wv*8.
//  - Epilogue peeled: no wasted wrap-around loads on the last window pair.
//  - Everything else identical to R11: 8-lane clusters/128B, RPT=8, plain loads,
//    LDS [slot][w] broadcast weights (72KB), launch_bounds(256,1), grid 256.

#define COMP_ISSUE(BUFC, JCUR, BUFL, JNEXT)                                    \
    {                                                                          \
        const f32x4* wp = &Wl[((JCUR) * 8 + c) * NW];                          \
        _Pragma("unroll")                                                      \
        for (int w = 0; w < NW; ++w) {                                         \
            if (w >= 1 && w <= RPT)                                            \
                BUFL[w - 1] = *reinterpret_cast<const f32x4*>(                 \
                    px[w - 1] + (size_t)(JNEXT) * 32);                         \
            f32x4 wf = wp[w];                                                  \
            _Pragma("unroll")                                                  \
            for (int k = 0; k < RPT; ++k) {                                    \
                float a = acc[k][w];                                           \
                a = fmaf(BUFC[k].x, wf.x, a);                                  \
                a = fmaf(BUFC[k].y, wf.y, a);                                  \
                a = fmaf(BUFC[k].z, wf.z, a);                                  \
                a = fmaf(BUFC[k].w, wf.w, a);                                  \
                acc[k][w] = a;                                                 \
            }                                                                  \
            __builtin_amdgcn_sched_group_barrier(0x002, 32, 0); /* 32 VALU */  \
            if (w >= 1 && w <= RPT)                                            \
                __builtin_amdgcn_sched_group_barrier(0x020, 1, 0); /* 1 VMEM */\
        }                                                                      \
    }

#define COMP_ONLY(BUFC, JCUR)                                                  \
    {                                                                          \
        const f32x4* wq = &Wl[((JCUR) * 8 + c) * NW];                          \
        _Pragma("unroll")                                                      \
        for (int w = 0; w < NW; ++w) {                                         \
            f32x4 wf = wq[w];                                                  \
            _Pragma("unroll")                                                  \
            for (int k = 0; k < RPT; ++k) {                                    \
                float a = acc[k][w];                                           \
                a = fmaf(BUFC[k].x, wf.x, a);                                  \
                a = fmaf(BUFC[k].y, wf.y, a);                                  \
                a = fmaf(BUFC[k].z, wf.z, a);                                  \
                a = fmaf(BUFC[k].w, wf.w, a);                                  \
                acc[k][w] = a;                                                 \
            }                                                                  \
        }                                                                      \
    }

__global__ __launch_bounds__(NTHREADS, 1)
void hardmoe_kernel(const float* __restrict__ cls,
                    const float* __restrict__ gate_w,
                    const float* __restrict__ gate_b,
                    const float* __restrict__ expert_w,
                    const float* __restrict__ expert_b,
                    float* __restrict__ out, int B)
{
    __shared__ f32x4 Wl[256 * NW];   // 72 KB

    const int t = threadIdx.x;

    // ---- Stage weights: thread t owns f4-slot s=t for all 18 w ----
    {
        const int s = t;
#pragma unroll
        for (int w = 0; w < NW; ++w) {
            const float* src = (w < 6) ? (gate_w + (size_t)w * HDIM)
                                       : (expert_w + (size_t)(w - 6) * HDIM);
            Wl[s * NW + w] = *(reinterpret_cast<const f32x4*>(src) + s);
        }
    }

    // ---- Biases (uniform -> scalar) ----
    float gb[6], eb[12];
#pragma unroll
    for (int e = 0; e < 6; ++e) gb[e] = gate_b[e];
#pragma unroll
    for (int k = 0; k < 12; ++k) eb[k] = expert_b[k];

    __syncthreads();

    const int wv = t >> 6;       // wave 0..3
    const int l  = t & 63;
    const int s8 = l >> 3;       // cluster 0..7
    const int c  = l & 7;        // col sublane 0..7

    // Full-residue phase: blk*9 covers all 32 (gcd(9,32)=1); wv*8 spreads waves.
    const int phase = (blockIdx.x * 9 + (wv << 3)) & (NJ - 1);

    const int wavebase = blockIdx.x * ROWS_PER_BLOCK + wv * 64;

    const float* px[RPT];
    int rows[RPT];
#pragma unroll
    for (int k = 0; k < RPT; ++k) {
        int r = wavebase + k * 8 + s8;
        rows[k] = r;
        int rc = r < B ? r : B - 1;
        px[k] = cls + (size_t)rc * HDIM + c * 4;
    }

    float acc[RPT][NW];
#pragma unroll
    for (int k = 0; k < RPT; ++k)
#pragma unroll
        for (int w = 0; w < NW; ++w) acc[k][w] = 0.f;

    f32x4 xA[RPT], xB[RPT];
#pragma unroll
    for (int k = 0; k < RPT; ++k)
        xA[k] = *reinterpret_cast<const f32x4*>(px[k] + (size_t)phase * 32);

    // Main loop: windows 0..NJ-3 with smoothed prefetch of the next window.
    for (int jj = 0; jj < NJ - 2; jj += 2) {
        const int ja = (jj + phase) & (NJ - 1);
        const int jb = (jj + 1 + phase) & (NJ - 1);
        const int jc = (jj + 2 + phase) & (NJ - 1);
        COMP_ISSUE(xA, ja, xB, jb);   // compute ja, spread-issue loads for jb
        COMP_ISSUE(xB, jb, xA, jc);   // compute jb, spread-issue loads for jc
    }
    // Peeled epilogue: last two windows, no wrap-around prefetch.
    {
        const int ja = (NJ - 2 + phase) & (NJ - 1);
        const int jb = (NJ - 1 + phase) & (NJ - 1);
        COMP_ISSUE(xA, ja, xB, jb);
        COMP_ONLY(xB, jb);
    }

    // ---- Reduce across the 8-lane cluster: xor 1,2,4 ----
#pragma unroll
    for (int k = 0; k < RPT; ++k)
#pragma unroll
        for (int w = 0; w < NW; ++w) {
            float v = acc[k][w];
            v += __shfl_xor(v, 1);
            v += __shfl_xor(v, 2);
            v += __shfl_xor(v, 4);
            acc[k][w] = v;
        }

    // ---- Per row: gate argmax (strict >, first-max tiebreak) + expert select ----
#pragma unroll
    for (int k = 0; k < RPT; ++k) {
        float best = acc[k][0] + gb[0];
        int idx = 0;
#pragma unroll
        for (int e = 1; e < 6; ++e) {
            float v = acc[k][e] + gb[e];
            if (v > best) { best = v; idx = e; }
        }
        float o0 = 0.f, o1 = 0.f;
#pragma unroll
        for (int e = 0; e < 6; ++e) {
            bool m = (idx == e);
            o0 = m ? (acc[k][6 + 2 * e] + eb[2 * e])     : o0;
            o1 = m ? (acc[k][7 + 2 * e] + eb[2 * e + 1]) : o1;
        }
        if (c == 0 && rows[k] < B)
            *reinterpret_cast<float2*>(out + (size_t)rows[k] * 2) = make_float2(o0, o1);
    }
}

extern "C" void kernel_launch(void* const* d_in, const int* in_sizes, int n_in,
                              void* d_out, int out_size, void* d_ws, size_t ws_size,
                              hipStream_t stream) {
    const float* cls      = (const float*)d_in[0];
    const float* gate_w   = (const float*)d_in[1];
    const float* gate_b   = (const float*)d_in[2];
    const float* expert_w = (const float*)d_in[3];
    const float* expert_b = (const float*)d_in[4];
    float* out = (float*)d_out;

    const int B = in_sizes[0] / HDIM;
    const int grid = (B + ROWS_PER_BLOCK - 1) / ROWS_PER_BLOCK;

    hardmoe_kernel<<<grid, NTHREADS, 0, stream>>>(cls, gate_w, gate_b,
                                                  expert_w, expert_b, out, B);
}

// Round 14
// 52.121 us; speedup vs baseline: 1.7202x; 1.7202x over previous
//
#include <hip/hip_runtime.h>

#define HDIM 1024
#define NW 18                 // 6 gate rows + 12 expert rows (e*2+l)
#define NTHREADS 256
#define RPT 8                 // rows per lane
#define ROWS_PER_BLOCK 256    // 4 waves x 64 rows
#define NJ 32                 // j-steps of 32 floats (128B) per row

typedef float f32x4 __attribute__((ext_vector_type(4)));

// R14 = R11 (best, 51.3us) + prologue overlap + full-residue phase.
//  - First x-window prefetch issues BEFORE weight staging (registers only, no
//    LDS dependency) -> HBM latency of the first window hides under the 18
//    weight loads + barrier instead of after them.
//  - Phase: blk*9 (gcd(9,32)=1 -> all 32 residues) + wv*8 (was 16 even-only).
//  - Everything else byte-identical to R11: 8-lane clusters/128B chunks, RPT=8,
//    plain (non-nt) loads, LDS [slot][w] f32x4 broadcast weights (72KB),
//    distance-1 static double buffer, launch_bounds(256,1), grid 256.
__global__ __launch_bounds__(NTHREADS, 1)
void hardmoe_kernel(const float* __restrict__ cls,
                    const float* __restrict__ gate_w,
                    const float* __restrict__ gate_b,
                    const float* __restrict__ expert_w,
                    const float* __restrict__ expert_b,
                    float* __restrict__ out, int B)
{
    __shared__ f32x4 Wl[256 * NW];   // 72 KB

    const int t  = threadIdx.x;
    const int wv = t >> 6;       // wave 0..3
    const int l  = t & 63;
    const int s8 = l >> 3;       // cluster 0..7
    const int c  = l & 7;        // col sublane 0..7

    // Full-residue phase: blk*9 covers all 32 (gcd(9,32)=1); wv*8 spreads waves.
    const int phase = (blockIdx.x * 9 + (wv << 3)) & (NJ - 1);

    const int wavebase = blockIdx.x * ROWS_PER_BLOCK + wv * 64;

    const float* px[RPT];
    int rows[RPT];
#pragma unroll
    for (int k = 0; k < RPT; ++k) {
        int r = wavebase + k * 8 + s8;
        rows[k] = r;
        int rc = r < B ? r : B - 1;
        px[k] = cls + (size_t)rc * HDIM + c * 4;
    }

    // ---- Issue first x-window prefetch BEFORE weight staging (overlap) ----
    f32x4 xA[RPT], xB[RPT];
#pragma unroll
    for (int k = 0; k < RPT; ++k)
        xA[k] = *reinterpret_cast<const f32x4*>(px[k] + (size_t)phase * 32);

    // ---- Stage weights: thread t owns f4-slot s=t for all 18 w ----
    {
        const int s = t;
#pragma unroll
        for (int w = 0; w < NW; ++w) {
            const float* src = (w < 6) ? (gate_w + (size_t)w * HDIM)
                                       : (expert_w + (size_t)(w - 6) * HDIM);
            Wl[s * NW + w] = *(reinterpret_cast<const f32x4*>(src) + s);
        }
    }

    // ---- Biases (uniform -> scalar) ----
    float gb[6], eb[12];
#pragma unroll
    for (int e = 0; e < 6; ++e) gb[e] = gate_b[e];
#pragma unroll
    for (int k = 0; k < 12; ++k) eb[k] = expert_b[k];

    __syncthreads();

    float acc[RPT][NW];
#pragma unroll
    for (int k = 0; k < RPT; ++k)
#pragma unroll
        for (int w = 0; w < NW; ++w) acc[k][w] = 0.f;

    for (int jj = 0; jj < NJ; jj += 2) {
        const int ja = (jj + phase) & (NJ - 1);
        const int jb = (jj + 1 + phase) & (NJ - 1);
        const int jc = (jj + 2 + phase) & (NJ - 1);

        // prefetch column jb
#pragma unroll
        for (int k = 0; k < RPT; ++k)
            xB[k] = *reinterpret_cast<const f32x4*>(px[k] + (size_t)jb * 32);
        // compute column ja with xA
        {
            const f32x4* wp = &Wl[(ja * 8 + c) * NW];
#pragma unroll
            for (int w = 0; w < NW; ++w) {
                f32x4 wf = wp[w];
#pragma unroll
                for (int k = 0; k < RPT; ++k) {
                    float a = acc[k][w];
                    a = fmaf(xA[k].x, wf.x, a);
                    a = fmaf(xA[k].y, wf.y, a);
                    a = fmaf(xA[k].z, wf.z, a);
                    a = fmaf(xA[k].w, wf.w, a);
                    acc[k][w] = a;
                }
            }
        }
        // prefetch column jc
        if (jj + 2 < NJ) {
#pragma unroll
            for (int k = 0; k < RPT; ++k)
                xA[k] = *reinterpret_cast<const f32x4*>(px[k] + (size_t)jc * 32);
        }
        // compute column jb with xB
        {
            const f32x4* wq = &Wl[(jb * 8 + c) * NW];
#pragma unroll
            for (int w = 0; w < NW; ++w) {
                f32x4 wf = wq[w];
#pragma unroll
                for (int k = 0; k < RPT; ++k) {
                    float a = acc[k][w];
                    a = fmaf(xB[k].x, wf.x, a);
                    a = fmaf(xB[k].y, wf.y, a);
                    a = fmaf(xB[k].z, wf.z, a);
                    a = fmaf(xB[k].w, wf.w, a);
                    acc[k][w] = a;
                }
            }
        }
    }

    // ---- Reduce across the 8-lane cluster: xor 1,2,4 ----
#pragma unroll
    for (int k = 0; k < RPT; ++k)
#pragma unroll
        for (int w = 0; w < NW; ++w) {
            float v = acc[k][w];
            v += __shfl_xor(v, 1);
            v += __shfl_xor(v, 2);
            v += __shfl_xor(v, 4);
            acc[k][w] = v;
        }

    // ---- Per row: gate argmax (strict >, first-max tiebreak) + expert select ----
#pragma unroll
    for (int k = 0; k < RPT; ++k) {
        float best = acc[k][0] + gb[0];
        int idx = 0;
#pragma unroll
        for (int e = 1; e < 6; ++e) {
            float v = acc[k][e] + gb[e];
            if (v > best) { best = v; idx = e; }
        }
        float o0 = 0.f, o1 = 0.f;
#pragma unroll
        for (int e = 0; e < 6; ++e) {
            bool m = (idx == e);
            o0 = m ? (acc[k][6 + 2 * e] + eb[2 * e])     : o0;
            o1 = m ? (acc[k][7 + 2 * e] + eb[2 * e + 1]) : o1;
        }
        if (c == 0 && rows[k] < B)
            *reinterpret_cast<float2*>(out + (size_t)rows[k] * 2) = make_float2(o0, o1);
    }
}

extern "C" void kernel_launch(void* const* d_in, const int* in_sizes, int n_in,
                              void* d_out, int out_size, void* d_ws, size_t ws_size,
                              hipStream_t stream) {
    const float* cls      = (const float*)d_in[0];
    const float* gate_w   = (const float*)d_in[1];
    const float* gate_b   = (const float*)d_in[2];
    const float* expert_w = (const float*)d_in[3];
    const float* expert_b = (const float*)d_in[4];
    float* out = (float*)d_out;

    const int B = in_sizes[0] / HDIM;
    const int grid = (B + ROWS_PER_BLOCK - 1) / ROWS_PER_BLOCK;

    hardmoe_kernel<<<grid, NTHREADS, 0, stream>>>(cls, gate_w, gate_b,
                                                  expert_w, expert_b, out, B);
}

// Round 15
// 51.946 us; speedup vs baseline: 1.7260x; 1.0034x over previous
//
#include <hip/hip_runtime.h>

#define HDIM 1024
#define NW 18                 // 6 gate rows + 12 expert rows (e*2+l)
#define NTHREADS 256
#define RPT 8                 // rows per lane
#define ROWS_PER_BLOCK 256    // 4 waves x 64 rows
#define NJ 32                 // j-steps of 32 floats (128B) per row

typedef float f32x4 __attribute__((ext_vector_type(4)));

// R15 = R11 verbatim (best measured: 51.3us, 5.2TB/s delivered, 83% of copy BW).
//  - Final configuration after 14 rounds of single-variable testing:
//    * weights LDS-broadcast [slot][w] f32x4 (72KB), staged once per block
//    * 8-lane clusters, 128B contiguous chunk per row-touch, RPT=8 rows/lane
//    * inter-wave column phase rotation (DRAM channel decorrelation, +13%)
//    * plain (non-nontemporal) loads (L2/L3 retention on replays, +9%)
//    * distance-1 static double buffer, launch_bounds(256,1), grid 256
//  - Refuted levers (do not revisit): TLP x2, 256B chunks x2, in-wave phase,
//    sched_group_barrier smoothing, prologue overlap, LDS-free weights.
__global__ __launch_bounds__(NTHREADS, 1)
void hardmoe_kernel(const float* __restrict__ cls,
                    const float* __restrict__ gate_w,
                    const float* __restrict__ gate_b,
                    const float* __restrict__ expert_w,
                    const float* __restrict__ expert_b,
                    float* __restrict__ out, int B)
{
    __shared__ f32x4 Wl[256 * NW];   // 72 KB

    const int t = threadIdx.x;

    // ---- Stage weights: thread t owns f4-slot s=t for all 18 w ----
    {
        const int s = t;
#pragma unroll
        for (int w = 0; w < NW; ++w) {
            const float* src = (w < 6) ? (gate_w + (size_t)w * HDIM)
                                       : (expert_w + (size_t)(w - 6) * HDIM);
            Wl[s * NW + w] = *(reinterpret_cast<const f32x4*>(src) + s);
        }
    }

    // ---- Biases (uniform -> scalar) ----
    float gb[6], eb[12];
#pragma unroll
    for (int e = 0; e < 6; ++e) gb[e] = gate_b[e];
#pragma unroll
    for (int k = 0; k < 12; ++k) eb[k] = expert_b[k];

    __syncthreads();

    const int wv = t >> 6;       // wave 0..3
    const int l  = t & 63;
    const int s8 = l >> 3;       // cluster 0..7
    const int c  = l & 7;        // col sublane 0..7

    // Even phase in [0,32), spread over blocks and waves (R7's proven lever).
    const int phase = ((blockIdx.x << 3) + (wv << 1)) & (NJ - 1);

    const int wavebase = blockIdx.x * ROWS_PER_BLOCK + wv * 64;

    const float* px[RPT];
    int rows[RPT];
#pragma unroll
    for (int k = 0; k < RPT; ++k) {
        int r = wavebase + k * 8 + s8;
        rows[k] = r;
        int rc = r < B ? r : B - 1;
        px[k] = cls + (size_t)rc * HDIM + c * 4;
    }

    float acc[RPT][NW];
#pragma unroll
    for (int k = 0; k < RPT; ++k)
#pragma unroll
        for (int w = 0; w < NW; ++w) acc[k][w] = 0.f;

    f32x4 xA[RPT], xB[RPT];
#pragma unroll
    for (int k = 0; k < RPT; ++k)
        xA[k] = *reinterpret_cast<const f32x4*>(px[k] + (size_t)phase * 32);

    for (int jj = 0; jj < NJ; jj += 2) {
        const int ja = (jj + phase) & (NJ - 1);
        const int jb = (jj + 1 + phase) & (NJ - 1);
        const int jc = (jj + 2 + phase) & (NJ - 1);

        // prefetch column jb
#pragma unroll
        for (int k = 0; k < RPT; ++k)
            xB[k] = *reinterpret_cast<const f32x4*>(px[k] + (size_t)jb * 32);
        // compute column ja with xA
        {
            const f32x4* wp = &Wl[(ja * 8 + c) * NW];
#pragma unroll
            for (int w = 0; w < NW; ++w) {
                f32x4 wf = wp[w];
#pragma unroll
                for (int k = 0; k < RPT; ++k) {
                    float a = acc[k][w];
                    a = fmaf(xA[k].x, wf.x, a);
                    a = fmaf(xA[k].y, wf.y, a);
                    a = fmaf(xA[k].z, wf.z, a);
                    a = fmaf(xA[k].w, wf.w, a);
                    acc[k][w] = a;
                }
            }
        }
        // prefetch column jc
        if (jj + 2 < NJ) {
#pragma unroll
            for (int k = 0; k < RPT; ++k)
                xA[k] = *reinterpret_cast<const f32x4*>(px[k] + (size_t)jc * 32);
        }
        // compute column jb with xB
        {
            const f32x4* wq = &Wl[(jb * 8 + c) * NW];
#pragma unroll
            for (int w = 0; w < NW; ++w) {
                f32x4 wf = wq[w];
#pragma unroll
                for (int k = 0; k < RPT; ++k) {
                    float a = acc[k][w];
                    a = fmaf(xB[k].x, wf.x, a);
                    a = fmaf(xB[k].y, wf.y, a);
                    a = fmaf(xB[k].z, wf.z, a);
                    a = fmaf(xB[k].w, wf.w, a);
                    acc[k][w] = a;
                }
            }
        }
    }

    // ---- Reduce across the 8-lane cluster: xor 1,2,4 ----
#pragma unroll
    for (int k = 0; k < RPT; ++k)
#pragma unroll
        for (int w = 0; w < NW; ++w) {
            float v = acc[k][w];
            v += __shfl_xor(v, 1);
            v += __shfl_xor(v, 2);
            v += __shfl_xor(v, 4);
            acc[k][w] = v;
        }

    // ---- Per row: gate argmax (strict >, first-max tiebreak) + expert select ----
#pragma unroll
    for (int k = 0; k < RPT; ++k) {
        float best = acc[k][0] + gb[0];
        int idx = 0;
#pragma unroll
        for (int e = 1; e < 6; ++e) {
            float v = acc[k][e] + gb[e];
            if (v > best) { best = v; idx = e; }
        }
        float o0 = 0.f, o1 = 0.f;
#pragma unroll
        for (int e = 0; e < 6; ++e) {
            bool m = (idx == e);
            o0 = m ? (acc[k][6 + 2 * e] + eb[2 * e])     : o0;
            o1 = m ? (acc[k][7 + 2 * e] + eb[2 * e + 1]) : o1;
        }
        if (c == 0 && rows[k] < B)
            *reinterpret_cast<float2*>(out + (size_t)rows[k] * 2) = make_float2(o0, o1);
    }
}

extern "C" void kernel_launch(void* const* d_in, const int* in_sizes, int n_in,
                              void* d_out, int out_size, void* d_ws, size_t ws_size,
                              hipStream_t stream) {
    const float* cls      = (const float*)d_in[0];
    const float* gate_w   = (const float*)d_in[1];
    const float* gate_b   = (const float*)d_in[2];
    const float* expert_w = (const float*)d_in[3];
    const float* expert_b = (const float*)d_in[4];
    float* out = (float*)d_out;

    const int B = in_sizes[0] / HDIM;
    const int grid = (B + ROWS_PER_BLOCK - 1) / ROWS_PER_BLOCK;

    hardmoe_kernel<<<grid, NTHREADS, 0, stream>>>(cls, gate_w, gate_b,
                                                  expert_w, expert_b, out, B);
}